// Round 12
// baseline (124.387 us; speedup 1.0000x reference)
//
#include <hip/hip_runtime.h>

#define BATCH 64
#define NN 256
// Scaled DP domain: V' = V * CSC, CSC = (1/gamma)*log2(e), gamma = 0.01.
#define CSC   144.26950408889634f
#define RCSC  0.0069314718055994531f   // 1/CSC = gamma*ln(2)
#define SQC   12.011224079f            // sqrt(CSC): T,o pre-scaled so x*x = CSC*(T-o)^2
#define BIGS  1.4426950408889634e10f   // 1e8 * CSC (scaled boundary)

// TWO BATCHES PER WAVE, interleaved in one instruction stream. R10's proven
// structure and schedule EXACTLY (4 waves/batch-pair, 1 row/lane/batch, skew
// S=12, 547 iters, barrier every 8 iters, 16-slot ring, q-pipeline with read
// age 8 / consume age 13, RD(7)/RD(15) hoisted early) — payloads widened to
// carry both batches: ring float2 -> float4 (nvA,ntA,nvB,ntB), o staged as
// float2 (oA[j], oB[j]) so the same broadcast ds_read serves both batches.
//
// WHY: at 1 wave/SIMD, ~115 of 185 cyc/iter is exposed dependence latency
// (exp2 -> sum -> log -> nv; rcp -> nt) with no independent in-wave work to
// fill it. Two independent DP chains alternated A,B in ONE stream let the
// compiler's latency-driven scheduler put B's DPP/min3/exp2 issue inside A's
// log-wait. R2's 2-wave version proved cross-stream fill works (1.44x
// per-SIMD) but lost to same-PC correlated stalls + full duplication; here
// the interleave is anti-correlated by construction and dr/loop/barrier/
// o-address/ring-op are shared (issue ~1.7x, not 2x). min3 + sqrt(CSC)
// pre-scale kept from R11 (both proven absmax-0).
//
// Ring safety = R10's proof verbatim (slots, ages, barrier-straddle all
// unchanged; only the payload width differs). BIG self-propagation kills all
// wedge cells per batch exactly as in R0. o zero-padding covers wedge columns
// for both batches (float2 zeros). Grid: 32 blocks, block = batches 2k,2k+1.

__device__ __forceinline__ float shr1(float x, float old) {
    return __int_as_float(__builtin_amdgcn_update_dpp(
        __float_as_int(old), __float_as_int(x), 0x138, 0xF, 0xF, false));
}

__device__ __forceinline__ float min3f(float a, float b, float c) {
    float d;
    asm("v_min3_f32 %0, %1, %2, %3" : "=v"(d) : "v"(a), "v"(b), "v"(c));
    return d;
}

// One interleaved double-cell (batch A and batch B at the same (row,col)).
// QV: float4 (A-v, A-u, B-v, B-u) from the q pipeline; OA/OB: o injections.
#define ITER(J, OA, OB, QV) {                                        \
    float sAa = shr1(Aa, (QV).x);                                    \
    float sUa = shr1(Ua, (QV).y);                                    \
    float sAb = shr1(Ab, (QV).z);                                    \
    float sUb = shr1(Ub, (QV).w);                                    \
    oca = shr1(oca, OA);                                             \
    ocb = shr1(ocb, OB);                                             \
    float ma  = min3f(Aa, psAa, sAa);                                \
    float mb  = min3f(Ab, psAb, sAb);                                \
    float ela = __builtin_amdgcn_exp2f(ma - Aa);                     \
    float elb = __builtin_amdgcn_exp2f(mb - Ab);                     \
    float eda = __builtin_amdgcn_exp2f(ma - psAa);                   \
    float edb = __builtin_amdgcn_exp2f(mb - psAb);                   \
    float eua = __builtin_amdgcn_exp2f(ma - sAa);                    \
    float eub = __builtin_amdgcn_exp2f(mb - sAb);                    \
    float sa  = ela + eda + eua;                                     \
    float sb  = elb + edb + eub;                                     \
    float xa  = Ta - oca;                                            \
    float xb  = Tb - ocb;                                            \
    float nva = fmaf(xa, xa, ma - __builtin_amdgcn_logf(sa));        \
    float nvb = fmaf(xb, xb, mb - __builtin_amdgcn_logf(sb));        \
    float numa = fmaf(ela, Ua, fmaf(eda, psUa, eua * sUa));          \
    float numb = fmaf(elb, Ub, fmaf(edb, psUb, eub * sUb));          \
    float d2 = dr * dr;                                              \
    float nta = fmaf(numa, __builtin_amdgcn_rcpf(sa), d2);           \
    float ntb = fmaf(numb, __builtin_amdgcn_rcpf(sb), d2);           \
    if (l63) ringw[(J)] = make_float4(nva, nta, nvb, ntb);           \
    psAa = sAa; psUa = sUa; Aa = nva; Ua = nta;                      \
    psAb = sAb; psUb = sUb; Ab = nvb; Ub = ntb;                      \
    dr -= 1.0f;                                                      \
}

#define RD(J, QD) { QD = ringr[((J) + 8) & 15]; }

// 16-iter phase on o-bank F (8 float4 = 16 columns, both batches).
#define PHASE(F0,F1,F2,F3,F4,F5,F6,F7)                               \
    ITER(0,  F0.x, F0.y, q3) RD(0,  q0)                              \
    ITER(1,  F0.z, F0.w, q4) RD(1,  q1)                              \
    ITER(2,  F1.x, F1.y, q5) RD(2,  q2)                              \
    ITER(3,  F1.z, F1.w, q6) RD(3,  q3)                              \
    ITER(4,  F2.x, F2.y, q7) RD(4,  q4)                              \
    ITER(5,  F2.z, F2.w, q0) RD(5,  q5)                              \
    ITER(6,  F3.x, F3.y, q1) RD(6,  q6) RD(7, q7)                    \
    ITER(7,  F3.z, F3.w, q2)                                         \
    __syncthreads();                                                 \
    ITER(8,  F4.x, F4.y, q3) RD(8,  q0)                              \
    ITER(9,  F4.z, F4.w, q4) RD(9,  q1)                              \
    ITER(10, F5.x, F5.y, q5) RD(10, q2)                              \
    ITER(11, F5.z, F5.w, q6) RD(11, q3)                              \
    ITER(12, F6.x, F6.y, q7) RD(12, q4)                              \
    ITER(13, F6.z, F6.w, q0) RD(13, q5)                              \
    ITER(14, F7.x, F7.y, q1) RD(14, q6) RD(15, q7)                   \
    ITER(15, F7.z, F7.w, q2)                                         \
    __syncthreads();

__global__ __launch_bounds__(256) void dilate_fused(
    const float* __restrict__ y_pred,
    const float* __restrict__ y_true,
    float* __restrict__ out)
{
    const int bA  = blockIdx.x * 2;      // batch A
    const int bB  = bA + 1;              // batch B
    const int tid = threadIdx.x;
    const int w   = tid >> 6;
    const int l   = tid & 63;
    const bool l63 = (l == 63);

    __shared__ float2 o_lds[1088];   // (oA,oB)*SQC at [512,768); zeros elsewhere
    __shared__ float4 ring[5][16];   // [row w (4 = const BIGS row)][slot]

    const float4 z4 = make_float4(0.f, 0.f, 0.f, 0.f);
    float4* ol4 = (float4*)o_lds;    // 544 float4 = 1088 float2
    ol4[tid] = z4;                                   // float2 [0,512)
    if (tid < 160) ol4[384 + tid] = z4;              // float2 [768,1088)
    o_lds[512 + tid] = make_float2(y_pred[bA * NN + tid] * SQC,
                                   y_pred[bB * NN + tid] * SQC);
    if (tid < 80) ((float4*)ring)[tid] = make_float4(BIGS, 0.f, BIGS, 0.f);

    const float Ta = y_true[bA * NN + tid] * SQC;    // row i = tid+1
    const float Tb = y_true[bB * NN + tid] * SQC;
    __syncthreads();

    float Aa = BIGS, Ua = 0.f, Ab = BIGS, Ub = 0.f;
    float psAa = (tid == 0) ? 0.f : BIGS;            // V[0,0] corner
    float psAb = psAa;
    float psUa = 0.f, psUb = 0.f;
    float oca = 0.f, ocb = 0.f;
    float dr = (float)(2 * tid + 12 * w);            // (i - j) at n=0, shared
    const float4 qi = make_float4(BIGS, 0.f, BIGS, 0.f);
    float4 q0 = qi, q1 = qi, q2 = qi, q3 = qi, q4 = qi, q5 = qi, q6 = qi, q7 = qi;

    float4* ringw = ring[w];
    const float4* ringr = ring[(w == 0) ? 4 : (w - 1)];
    const float4* o4 = ((const float4*)o_lds) + (256 - 38 * w);  // f2 idx 512-76w

    float4 f0 = o4[0], f1 = o4[1], f2 = o4[2], f3 = o4[3],
           f4 = o4[4], f5 = o4[5], f6 = o4[6], f7 = o4[7];
    o4 += 8;
    float4 g0, g1, g2, g3, g4, g5, g6, g7;

    #pragma unroll 1
    for (int blk = 0; blk < 17; ++blk) {             // n = 0..543
        g0 = o4[0]; g1 = o4[1]; g2 = o4[2]; g3 = o4[3];
        g4 = o4[4]; g5 = o4[5]; g6 = o4[6]; g7 = o4[7];
        PHASE(f0, f1, f2, f3, f4, f5, f6, f7)
        f0 = o4[8];  f1 = o4[9];  f2 = o4[10]; f3 = o4[11];
        f4 = o4[12]; f5 = o4[13]; f6 = o4[14]; f7 = o4[15];
        o4 += 16;
        PHASE(g0, g1, g2, g3, g4, g5, g6, g7)
    }
    // peel n = 544..546 (wave 3 reaches cell (256,256) at n = 546): q3,q4,q5
    // hold values 531..533 (read >=1 barrier before loop end, R10 proof);
    // peel ring writes (slots 0..2) are never consumed; f-bank freshly loaded.
    ITER(0, f0.x, f0.y, q3)
    ITER(1, f0.z, f0.w, q4)
    ITER(2, f1.x, f1.y, q5)

    if (tid == 255) {                    // wave 3, lane 63: cell (256,256), both
        float lossA = 0.5f * (Aa * RCSC) * (1.0f / BATCH)
                    + 0.5f * Ua * (1.0f / ((float)BATCH * (float)(NN * NN)));
        float lossB = 0.5f * (Ab * RCSC) * (1.0f / BATCH)
                    + 0.5f * Ub * (1.0f / ((float)BATCH * (float)(NN * NN)));
        atomicAdd(out, lossA + lossB);
    }
}

extern "C" void kernel_launch(void* const* d_in, const int* in_sizes, int n_in,
                              void* d_out, int out_size, void* d_ws, size_t ws_size,
                              hipStream_t stream)
{
    const float* y_pred = (const float*)d_in[0];   // [64,256,1] -> o (columns)
    const float* y_true = (const float*)d_in[1];   // [64,256,1] -> t (rows)
    hipMemsetAsync(d_out, 0, sizeof(float), stream);
    dilate_fused<<<BATCH / 2, 256, 0, stream>>>(y_pred, y_true, (float*)d_out);
}

// Round 13
// 106.559 us; speedup vs baseline: 1.1673x; 1.1673x over previous
//
#include <hip/hip_runtime.h>

#define BATCH 64
#define NN 256
// Scaled DP domain: V' = V * CSC, CSC = (1/gamma)*log2(e), gamma = 0.01.
#define CSC   144.26950408889634f
#define RCSC  0.0069314718055994531f   // 1/CSC = gamma*ln(2)
#define SQC   12.011224079f            // sqrt(CSC): T,o pre-scaled so x*x = CSC*(T-o)^2
#define BIGS  1.4426950408889634e10f   // 1e8 * CSC (scaled boundary)

// R11 structure EXACTLY (4 waves/batch, 1 row/lane, skew S=12, 547 iters,
// barrier every 8 iters, paired float4 ring w/ q-pipeline read-age 8 /
// consume-age 13, f/g o-banks, 42.2us proven absmax-0) with the arithmetic
// core HAND-SCHEDULED in one inline-asm block per cell. Rationale (R12
// decomposition): issue = 92 cyc/iter (VALUBusy 50.8%/active-CU), barrier =
// 16, chain = 60-90 -> perfect schedule = 110-130/iter; measured 185. The
// gap is trans-latency exposure: compiler places exp2/log/rcp consumers too
// close. Asm order: DPPs -> (d2, dr fillers) -> min3 -> 3 subs -> 3 exp2
// back-to-back -> x filler -> s-adds -> log+rcp issued together -> 3
// num-fmas in the log/rcp shadow -> m-lg -> nv -> nt. Identical instruction
// set and rounding as R11 (absmax 0 expected). s_nop 1 guards the
// VALU-write->DPP-read hazard at block entry (prev cell's fma writes A/U).
// dr-1 as v_add_f32 dr, -1.0, dr (inline const must be src0 per ISA).
// Register allocation is left to the compiler via asm constraints.

#define CELLX(OINJ, QA, QB, PRE, POST) {                             \
    float sA = (QA), sU = (QB), ocn = (OINJ);                        \
    float m_, t1_, t2_, t3_, x_, d2_, s_, lg_, rc_, nm_;             \
    PRE                                                              \
    asm("s_nop 1\n\t"                                                \
        "v_mov_b32_dpp %[sA], %[A] wave_shr:1 row_mask:0xf bank_mask:0xf\n\t" \
        "v_mov_b32_dpp %[sU], %[U] wave_shr:1 row_mask:0xf bank_mask:0xf\n\t" \
        "v_mov_b32_dpp %[oc], %[ocs] wave_shr:1 row_mask:0xf bank_mask:0xf\n\t" \
        "v_mul_f32 %[d2], %[dr], %[dr]\n\t"                          \
        "v_add_f32 %[dr], -1.0, %[dr]\n\t"                           \
        "v_min3_f32 %[m], %[A], %[psA], %[sA]\n\t"                   \
        "v_sub_f32 %[t1], %[m], %[A]\n\t"                            \
        "v_sub_f32 %[t2], %[m], %[psA]\n\t"                          \
        "v_sub_f32 %[t3], %[m], %[sA]\n\t"                           \
        "v_exp_f32 %[t1], %[t1]\n\t"                                 \
        "v_exp_f32 %[t2], %[t2]\n\t"                                 \
        "v_exp_f32 %[t3], %[t3]\n\t"                                 \
        "v_sub_f32 %[x], %[T], %[oc]\n\t"                            \
        "v_add_f32 %[s], %[t1], %[t2]\n\t"                           \
        "v_add_f32 %[s], %[s], %[t3]\n\t"                            \
        "v_log_f32 %[lg], %[s]\n\t"                                  \
        "v_rcp_f32 %[rc], %[s]\n\t"                                  \
        "v_mul_f32 %[nm], %[t3], %[sU]\n\t"                          \
        "v_fma_f32 %[nm], %[t2], %[psU], %[nm]\n\t"                  \
        "v_fma_f32 %[nm], %[t1], %[U], %[nm]\n\t"                    \
        "v_sub_f32 %[m], %[m], %[lg]\n\t"                            \
        "v_fma_f32 %[A], %[x], %[x], %[m]\n\t"                       \
        "v_fma_f32 %[U], %[nm], %[rc], %[d2]\n\t"                    \
        : [A]"+v"(A), [U]"+v"(U), [sA]"+v"(sA), [sU]"+v"(sU),        \
          [oc]"+v"(ocn), [dr]"+v"(dr),                               \
          [m]"=&v"(m_), [t1]"=&v"(t1_), [t2]"=&v"(t2_),              \
          [t3]"=&v"(t3_), [x]"=&v"(x_), [d2]"=&v"(d2_),              \
          [s]"=&v"(s_), [lg]"=&v"(lg_), [rc]"=&v"(rc_),              \
          [nm]"=&v"(nm_)                                             \
        : [psA]"v"(psA), [psU]"v"(psU), [ocs]"v"(oc), [T]"v"(T));    \
    POST                                                             \
    psA = sA; psU = sU; oc = ocn;                                    \
}

#define CELL(OINJ, QA, QB) CELLX(OINJ, QA, QB, , )
#define CELL_W(OINJ, QA, QB, SLOT)                                   \
    CELLX(OINJ, QA, QB, float wv = A; float wu = U;,                 \
          if (l63) ringw[SLOT] = make_float4(wv, wu, A, U);)

__global__ __launch_bounds__(256) void dilate_fused(
    const float* __restrict__ y_pred,
    const float* __restrict__ y_true,
    float* __restrict__ out)
{
    const int b   = blockIdx.x;
    const int tid = threadIdx.x;
    const int w   = tid >> 6;
    const int l   = tid & 63;
    const bool l63 = (l == 63);

    __shared__ float  o_lds[1088];   // zeros | sqrt(CSC)*o at [512,768) | zeros
    __shared__ float4 ring[5][8];    // [row w (4 = const BIGS row)][pair slot]

    const float4 z4 = make_float4(0.f, 0.f, 0.f, 0.f);
    if (tid < 128) ((float4*)o_lds)[tid] = z4;                       // [0,512)
    if (tid >= 128 && tid < 208) ((float4*)o_lds)[tid + 64] = z4;    // [768,1088)
    if (tid < 64) {
        float4 ov = ((const float4*)(y_pred + b * NN))[tid];
        ov.x *= SQC; ov.y *= SQC; ov.z *= SQC; ov.w *= SQC;
        ((float4*)(o_lds + 512))[tid] = ov;                          // scaled o
    }
    if (tid < 40) ((float4*)ring)[tid] = make_float4(BIGS, 0.f, BIGS, 0.f);

    const float T = y_true[b * NN + tid] * SQC;                      // row i = tid+1
    __syncthreads();

    float A = BIGS, U = 0.f;
    float psA = (tid == 0) ? 0.f : BIGS;                             // V[0,0] corner
    float psU = 0.f;
    float oc = 0.f;
    float dr = (float)(2 * tid + 12 * w);                            // (i - j) at n=0
    const float4 qi = make_float4(BIGS, 0.f, BIGS, 0.f);
    float4 q0 = qi, q1 = qi, q2 = qi, q3 = qi;

    float4* ringw = ring[w];
    const float4* ringr = ring[(w == 0) ? 4 : (w - 1)];
    const float4* o4 = ((const float4*)o_lds) + (128 - 19 * w);      // 76w floats

    float4 fA = o4[0], fB = o4[1], fC = o4[2], fD = o4[3]; o4 += 4;
    float4 gA, gB, gC, gD;

    #pragma unroll 1
    for (int blk = 0; blk < 17; ++blk) {                             // n = 0..543
        gA = o4[0]; gB = o4[1]; gC = o4[2]; gD = o4[3];
        q0 = ringr[4]; CELL  (fA.x, q1.z, q1.w)
                       CELL_W(fA.y, q2.x, q2.y, 0)
        q1 = ringr[5]; CELL  (fA.z, q2.z, q2.w)
                       CELL_W(fA.w, q3.x, q3.y, 1)
        q2 = ringr[6]; CELL  (fB.x, q3.z, q3.w)
                       CELL_W(fB.y, q0.x, q0.y, 2)
        q3 = ringr[7]; CELL  (fB.z, q0.z, q0.w)
                       CELL_W(fB.w, q1.x, q1.y, 3)
        __syncthreads();
        q0 = ringr[0]; CELL  (fC.x, q1.z, q1.w)
                       CELL_W(fC.y, q2.x, q2.y, 4)
        q1 = ringr[1]; CELL  (fC.z, q2.z, q2.w)
                       CELL_W(fC.w, q3.x, q3.y, 5)
        q2 = ringr[2]; CELL  (fD.x, q3.z, q3.w)
                       CELL_W(fD.y, q0.x, q0.y, 6)
        q3 = ringr[3]; CELL  (fD.z, q0.z, q0.w)
                       CELL_W(fD.w, q1.x, q1.y, 7)
        __syncthreads();
        fA = o4[4]; fB = o4[5]; fC = o4[6]; fD = o4[7]; o4 += 8;
        q0 = ringr[4]; CELL  (gA.x, q1.z, q1.w)
                       CELL_W(gA.y, q2.x, q2.y, 0)
        q1 = ringr[5]; CELL  (gA.z, q2.z, q2.w)
                       CELL_W(gA.w, q3.x, q3.y, 1)
        q2 = ringr[6]; CELL  (gB.x, q3.z, q3.w)
                       CELL_W(gB.y, q0.x, q0.y, 2)
        q3 = ringr[7]; CELL  (gB.z, q0.z, q0.w)
                       CELL_W(gB.w, q1.x, q1.y, 3)
        __syncthreads();
        q0 = ringr[0]; CELL  (gC.x, q1.z, q1.w)
                       CELL_W(gC.y, q2.x, q2.y, 4)
        q1 = ringr[1]; CELL  (gC.z, q2.z, q2.w)
                       CELL_W(gC.w, q3.x, q3.y, 5)
        q2 = ringr[2]; CELL  (gD.x, q3.z, q3.w)
                       CELL_W(gD.y, q0.x, q0.y, 6)
        q3 = ringr[3]; CELL  (gD.z, q0.z, q0.w)
                       CELL_W(gD.w, q1.x, q1.y, 7)
        __syncthreads();
    }
    // peel n = 544..546 (wave 3 reaches cell (256,256) at n = 546):
    // q-elements follow the period-8 pattern (I'%8 = 0,1,2); no ring ops.
    CELL(fA.x, q1.z, q1.w)
    CELL(fA.y, q2.x, q2.y)
    CELL(fA.z, q2.z, q2.w)

    if (tid == 255) {                       // wave 3, lane 63: cell (256,256)
        float loss = 0.5f * (A * RCSC) * (1.0f / BATCH)
                   + 0.5f * U * (1.0f / ((float)BATCH * (float)(NN * NN)));
        atomicAdd(out, loss);
    }
}

extern "C" void kernel_launch(void* const* d_in, const int* in_sizes, int n_in,
                              void* d_out, int out_size, void* d_ws, size_t ws_size,
                              hipStream_t stream)
{
    const float* y_pred = (const float*)d_in[0];   // [64,256,1] -> o (columns)
    const float* y_true = (const float*)d_in[1];   // [64,256,1] -> t (rows)
    hipMemsetAsync(d_out, 0, sizeof(float), stream);
    dilate_fused<<<BATCH, 256, 0, stream>>>(y_pred, y_true, (float*)d_out);
}

// Round 14
// 95.075 us; speedup vs baseline: 1.3083x; 1.1208x over previous
//
#include <hip/hip_runtime.h>

#define BATCH 64
#define NN 256
// Scaled DP domain: V' = V * CSC, CSC = (1/gamma)*log2(e), gamma = 0.01.
#define CSC   144.26950408889634f
#define RCSC  0.0069314718055994531f   // 1/CSC = gamma*ln(2)
#define SQC   12.011224079f            // sqrt(CSC): T,o pre-scaled so x*x = CSC*(T-o)^2
#define BIGS  1.4426950408889634e10f   // 1e8 * CSC (scaled boundary)

// PROVEN BEST (R11, 42.2us dispatch, absmax 0). R10 structure (4 waves/batch,
// 1 row/lane, skew S=12, 547 iters, barrier every 8 iters, u=13) with four
// op-count cuts, numerics unchanged:
//  1. v_min3_f32 inline asm for m (2 fmin -> 1 op, shorter chain).
//  2. sqrt(CSC) pre-scale of T,o (kills CSC*x mul; R9-proven absmax 0).
//  3. 32-iter double body (f-bank I=0..15, g-bank I=16..31; loads write the
//     opposite bank) -> no fA=gA rotation movs.
//  4. PAIRED RING (float4 = nv,nt of values 2m,2m+1): write once per 2 iters
//     (odd n, slot m&7, static immediate), read once per 2 iters (even n,
//     pair m=(n-8)/2, slot m&7, q[m&3] of 4 float4 pipeline regs, period-8
//     static rotation). Consumption at iter n' uses value n'-13: pair
//     floor((n'-13)/2), element zw if n' even (v odd) else xy.
//     Safety (all proven for every v): write(pair m)@2m+1 -> read@2m+8: the
//     interval contains 4 consecutive evens -> always crosses a barrier
//     (barriers after n%8==7); slot reuse @2m+17 vs read @2m+8: gap 9 ->
//     barrier-separated; q reg loaded at I, consumed I+5/I+6, reloaded I+8.
// Peel n=544..546: consumes values 531..533 (pairs 265/266 read at n=538/540,
// written at 531/533, >=1 barrier before loop end); peel writes skipped
// (never consumed). o: per-wave base 512-76w, zero-padded [0,512)+[768,1088)
// covers all wedge columns; BIG self-propagation kills wedge cells exactly.
//
// SESSION LEDGER (why this is the floor): R13 hand-asm = serial cell = 237
// cyc/iter -> compiler's 185 already overlaps cells near-optimally. Budget:
// issue 92 (VALUBusy 50.8%/active-CU) + chain exposure ~75 + barrier ~16.
// Refuted alternatives: TLP (R2), 4 rows/lane (R3: 472 cyc/iter), lazy-V
// (R4/R6 NaN; R7 +clamps 60us), LDS reposition (R8/R9 null), 2-batch ILP
// (R12: wall 317/iter), hand asm (R13: 237). C=16 cadence nets ~0 by fit.

__device__ __forceinline__ float shr1(float x, float old) {
    return __int_as_float(__builtin_amdgcn_update_dpp(
        __float_as_int(old), __float_as_int(x), 0x138, 0xF, 0xF, false));
}

__device__ __forceinline__ float min3f(float a, float b, float c) {
    float d;
    asm("v_min3_f32 %0, %1, %2, %3" : "=v"(d) : "v"(a), "v"(b), "v"(c));
    return d;
}

#define CELLX(OINJ, QA, QB, PRE, POST) {                             \
    float sA = shr1(A, QA);                                          \
    float sU = shr1(U, QB);                                          \
    oc = shr1(oc, OINJ);                                             \
    PRE                                                              \
    float m  = min3f(A, psA, sA);                                    \
    float el = __builtin_amdgcn_exp2f(m - A);                        \
    float ed = __builtin_amdgcn_exp2f(m - psA);                      \
    float eu = __builtin_amdgcn_exp2f(m - sA);                       \
    float s  = el + ed + eu;                                         \
    float x  = T - oc;                                               \
    float nv = fmaf(x, x, m - __builtin_amdgcn_logf(s));             \
    float num = fmaf(el, U, fmaf(ed, psU, eu * sU));                 \
    float nt  = fmaf(num, __builtin_amdgcn_rcpf(s), dr * dr);        \
    POST                                                             \
    psA = sA; psU = sU; A = nv; U = nt; dr -= 1.0f;                  \
}

#define CELL(OINJ, QA, QB) CELLX(OINJ, QA, QB, , )
#define CELL_W(OINJ, QA, QB, SLOT)                                   \
    CELLX(OINJ, QA, QB, float wv = A; float wu = U;,                 \
          if (l63) ringw[SLOT] = make_float4(wv, wu, nv, nt);)

__global__ __launch_bounds__(256) void dilate_fused(
    const float* __restrict__ y_pred,
    const float* __restrict__ y_true,
    float* __restrict__ out)
{
    const int b   = blockIdx.x;
    const int tid = threadIdx.x;
    const int w   = tid >> 6;
    const int l   = tid & 63;
    const bool l63 = (l == 63);

    __shared__ float  o_lds[1088];   // zeros | sqrt(CSC)*o at [512,768) | zeros
    __shared__ float4 ring[5][8];    // [row w (4 = const BIGS row)][pair slot]

    const float4 z4 = make_float4(0.f, 0.f, 0.f, 0.f);
    if (tid < 128) ((float4*)o_lds)[tid] = z4;                       // [0,512)
    if (tid >= 128 && tid < 208) ((float4*)o_lds)[tid + 64] = z4;    // [768,1088)
    if (tid < 64) {
        float4 ov = ((const float4*)(y_pred + b * NN))[tid];
        ov.x *= SQC; ov.y *= SQC; ov.z *= SQC; ov.w *= SQC;
        ((float4*)(o_lds + 512))[tid] = ov;                          // scaled o
    }
    if (tid < 40) ((float4*)ring)[tid] = make_float4(BIGS, 0.f, BIGS, 0.f);

    const float T = y_true[b * NN + tid] * SQC;                      // row i = tid+1
    __syncthreads();

    float A = BIGS, U = 0.f;
    float psA = (tid == 0) ? 0.f : BIGS;                             // V[0,0] corner
    float psU = 0.f;
    float oc = 0.f;
    float dr = (float)(2 * tid + 12 * w);                            // (i - j) at n=0
    const float4 qi = make_float4(BIGS, 0.f, BIGS, 0.f);
    float4 q0 = qi, q1 = qi, q2 = qi, q3 = qi;

    float4* ringw = ring[w];
    const float4* ringr = ring[(w == 0) ? 4 : (w - 1)];
    const float4* o4 = ((const float4*)o_lds) + (128 - 19 * w);      // 76w floats

    float4 fA = o4[0], fB = o4[1], fC = o4[2], fD = o4[3]; o4 += 4;
    float4 gA, gB, gC, gD;

    #pragma unroll 1
    for (int blk = 0; blk < 17; ++blk) {                             // n = 0..543
        gA = o4[0]; gB = o4[1]; gC = o4[2]; gD = o4[3];
        q0 = ringr[4]; CELL  (fA.x, q1.z, q1.w)
                       CELL_W(fA.y, q2.x, q2.y, 0)
        q1 = ringr[5]; CELL  (fA.z, q2.z, q2.w)
                       CELL_W(fA.w, q3.x, q3.y, 1)
        q2 = ringr[6]; CELL  (fB.x, q3.z, q3.w)
                       CELL_W(fB.y, q0.x, q0.y, 2)
        q3 = ringr[7]; CELL  (fB.z, q0.z, q0.w)
                       CELL_W(fB.w, q1.x, q1.y, 3)
        __syncthreads();
        q0 = ringr[0]; CELL  (fC.x, q1.z, q1.w)
                       CELL_W(fC.y, q2.x, q2.y, 4)
        q1 = ringr[1]; CELL  (fC.z, q2.z, q2.w)
                       CELL_W(fC.w, q3.x, q3.y, 5)
        q2 = ringr[2]; CELL  (fD.x, q3.z, q3.w)
                       CELL_W(fD.y, q0.x, q0.y, 6)
        q3 = ringr[3]; CELL  (fD.z, q0.z, q0.w)
                       CELL_W(fD.w, q1.x, q1.y, 7)
        __syncthreads();
        fA = o4[4]; fB = o4[5]; fC = o4[6]; fD = o4[7]; o4 += 8;
        q0 = ringr[4]; CELL  (gA.x, q1.z, q1.w)
                       CELL_W(gA.y, q2.x, q2.y, 0)
        q1 = ringr[5]; CELL  (gA.z, q2.z, q2.w)
                       CELL_W(gA.w, q3.x, q3.y, 1)
        q2 = ringr[6]; CELL  (gB.x, q3.z, q3.w)
                       CELL_W(gB.y, q0.x, q0.y, 2)
        q3 = ringr[7]; CELL  (gB.z, q0.z, q0.w)
                       CELL_W(gB.w, q1.x, q1.y, 3)
        __syncthreads();
        q0 = ringr[0]; CELL  (gC.x, q1.z, q1.w)
                       CELL_W(gC.y, q2.x, q2.y, 4)
        q1 = ringr[1]; CELL  (gC.z, q2.z, q2.w)
                       CELL_W(gC.w, q3.x, q3.y, 5)
        q2 = ringr[2]; CELL  (gD.x, q3.z, q3.w)
                       CELL_W(gD.y, q0.x, q0.y, 6)
        q3 = ringr[3]; CELL  (gD.z, q0.z, q0.w)
                       CELL_W(gD.w, q1.x, q1.y, 7)
        __syncthreads();
    }
    // peel n = 544..546 (wave 3 reaches cell (256,256) at n = 546):
    // q-elements follow the period-8 pattern (I'%8 = 0,1,2); no ring ops.
    CELL(fA.x, q1.z, q1.w)
    CELL(fA.y, q2.x, q2.y)
    CELL(fA.z, q2.z, q2.w)

    if (tid == 255) {                       // wave 3, lane 63: cell (256,256)
        float loss = 0.5f * (A * RCSC) * (1.0f / BATCH)
                   + 0.5f * U * (1.0f / ((float)BATCH * (float)(NN * NN)));
        atomicAdd(out, loss);
    }
}

extern "C" void kernel_launch(void* const* d_in, const int* in_sizes, int n_in,
                              void* d_out, int out_size, void* d_ws, size_t ws_size,
                              hipStream_t stream)
{
    const float* y_pred = (const float*)d_in[0];   // [64,256,1] -> o (columns)
    const float* y_true = (const float*)d_in[1];   // [64,256,1] -> t (rows)
    hipMemsetAsync(d_out, 0, sizeof(float), stream);
    dilate_fused<<<BATCH, 256, 0, stream>>>(y_pred, y_true, (float*)d_out);
}